// Round 14
// baseline (192.840 us; speedup 1.0000x reference)
//
#include <hip/hip_runtime.h>

// Problem constants
constexpr int B_   = 2;
constexpr int CIN  = 64;
constexpr int N    = 128;
constexpr int T    = 24;
constexpr int HID  = 64;
constexpr int COUT = 64;
constexpr int NT   = N * T;             // 3072
constexpr int BT   = B_ * T;            // 48
constexpr int ATT_BLOCKS = B_ * N;      // 256
constexpr int XT_BLOCKS  = 32;
constexpr int WF_BLOCKS  = 16;
constexpr int PREP_BLOCKS = ATT_BLOCKS + XT_BLOCKS + WF_BLOCKS;  // 304
constexpr int ALL_BLOCKS  = BT * 8;     // 384
constexpr int AMP = 30;                 // amplification factor (diagnostic)

typedef __attribute__((ext_vector_type(8))) short short8;
typedef __attribute__((ext_vector_type(4))) float f32x4;

__device__ inline unsigned short f2bf(float f) {
    unsigned u = __float_as_uint(f);
    return (unsigned short)((u + 0x7FFFu + ((u >> 16) & 1u)) >> 16);
}

// ---------------------------------------------------------------------------
// prep body (R13-identical), parameterized by block index + outputs.
// ---------------------------------------------------------------------------
__device__ __forceinline__ void prep_body(
    int blk, int tid,
    const float* __restrict__ x,  const float* __restrict__ att,
    const float* __restrict__ W1, const float* __restrict__ b1,
    const float* __restrict__ W2, const float* __restrict__ b2,
    unsigned* __restrict__ xT32, unsigned* __restrict__ attT32,
    float* __restrict__ asum_g,
    unsigned short* __restrict__ WfvT, unsigned short* __restrict__ WfhT,
    float* __restrict__ bvb2, float* __restrict__ bh,
    unsigned* smem_u32)
{
    if (blk < ATT_BLOCKS) {
        float* ts   = (float*)smem_u32;          // [128][25]
        float* psum = ts + 3200;                 // [24][8]
        const int b = blk >> 7;
        const int i = blk & 127;

        const float* ab = att + ((size_t)b * N + i) * NT;
#pragma unroll
        for (int u = 0; u < 12; ++u) {
            const int idx = tid + 256 * u;
            const int j = idx / T, t = idx - j * T;
            ts[j * 25 + t] = ab[idx];
        }
        __syncthreads();
#pragma unroll
        for (int u = 0; u < 6; ++u) {
            const int e2 = tid + 256 * u;
            const int t = e2 >> 6, jp = e2 & 63, j = jp * 2;
            const unsigned pk = (unsigned)f2bf(ts[j * 25 + t])
                              | ((unsigned)f2bf(ts[(j + 1) * 25 + t]) << 16);
            attT32[((size_t)(b * T + t) * N + i) * 64 + jp] = pk;
        }
        if (tid < 192) {
            const int t = tid >> 3, p = tid & 7;
            float s = 0.f;
#pragma unroll
            for (int q = 0; q < 16; ++q) s += ts[(p * 16 + q) * 25 + t];
            psum[t * 8 + p] = s;
        }
        __syncthreads();
        if (tid < T) {
            float s = 0.f;
#pragma unroll
            for (int p = 0; p < 8; ++p) s += psum[tid * 8 + p];
            asum_g[(size_t)(b * T + tid) * N + i] = s;
        }
    } else if (blk < ATT_BLOCKS + XT_BLOCKS) {
        const int tb = blk - ATT_BLOCKS;
        const int b  = tb >> 4;
        const int n0 = (tb & 15) * 8;
#pragma unroll
        for (int u = 0; u < 12; ++u) {
            const int vidx = tid + 256 * u;
            const int cp = vidx / 48, w48 = vidx - cp * 48;
            const float4 v = *(const float4*)(x + (size_t)(b * CIN + cp) * NT
                                              + n0 * T + w48 * 4);
            smem_u32[cp * 97 + w48 * 2]     = (unsigned)f2bf(v.x) | ((unsigned)f2bf(v.y) << 16);
            smem_u32[cp * 97 + w48 * 2 + 1] = (unsigned)f2bf(v.z) | ((unsigned)f2bf(v.w) << 16);
        }
        __syncthreads();
#pragma unroll
        for (int v = 0; v < 24; ++v) {
            const int oidx = tid + 256 * v;
            const int t = oidx >> 8, rem = oidx & 255;
            const int n = rem >> 5, cp = rem & 31;
            const int r = n * T + t;
            const unsigned w0 = smem_u32[(2 * cp) * 97 + (r >> 1)];
            const unsigned w1 = smem_u32[(2 * cp + 1) * 97 + (r >> 1)];
            const unsigned v0 = (r & 1) ? (w0 >> 16) : (w0 & 0xFFFFu);
            const unsigned v1 = (r & 1) ? (w1 >> 16) : (w1 & 0xFFFFu);
            xT32[((size_t)(b * T + t) * N + n0 + n) * 32 + cp] = v0 | (v1 << 16);
        }
    } else {
        const int wf   = blk - (ATT_BLOCKS + XT_BLOCKS);
        const int half = wf >> 3;
        const int c0   = (wf & 7) * 8;
        float* sW1 = (float*)smem_u32;          // [64][65]
        float* sW2 = sW1 + 64 * 65;             // [64][65]
#pragma unroll
        for (int u = 0; u < 16; ++u) {
            const int i = tid + 256 * u;
            const int r = i >> 6, q = i & 63;
            sW1[r * 65 + q] = W1[i];
            sW2[r * 65 + q] = W2[half * 4096 + i];
        }
        __syncthreads();

        const int c = c0 + (tid & 7);
        const int r = tid >> 3;
        float a0 = 0.f, a1 = 0.f;
#pragma unroll
        for (int q = 0; q < 64; ++q) {
            const float w2 = sW2[q * 65 + c];
            a0 += sW1[r * 65 + q] * w2;
            a1 += sW1[(r + 32) * 65 + q] * w2;
        }
        unsigned short* dst = half ? WfhT : WfvT;
        dst[c * 64 + r]      = f2bf(a0);
        dst[c * 64 + r + 32] = f2bf(a1);

        if (tid < 8) {
            const int cb = c0 + tid;
            float s = 0.f;
#pragma unroll
            for (int q = 0; q < 64; ++q) s += b1[q] * sW2[q * 65 + cb];
            if (half) bh[cb] = s;
            else      bvb2[cb] = s + b2[cb];
        }
    }
}

// ---------------------------------------------------------------------------
// k_all body (R13 + HOISTED phase-2 loads): att frags + asum loaded BEFORE
// the phase-1 MFMA chain so one latency epoch covers all global reads.
// ---------------------------------------------------------------------------
__device__ __forceinline__ void all_body(
    int blk, int tid,
    const unsigned short* __restrict__ xTb,
    const unsigned short* __restrict__ attTb,
    const unsigned short* __restrict__ WfvT,
    const unsigned short* __restrict__ WfhT,
    const float* __restrict__ bvb2, const float* __restrict__ bh,
    const float* __restrict__ asum_g,
    float* __restrict__ out,
    unsigned short (*mhT)[140])
{
    const int itile = blk & 7;
    const int bt    = blk >> 3;
    const int b     = bt / T;
    const int t     = bt - b * T;

    const int w    = tid >> 6;
    const int lane = tid & 63;
    const int c16  = lane & 15;
    const int q4   = lane >> 4;
    const int cc   = w * 16 + c16;

    // ---- HOISTED global loads (one latency epoch for everything) ----
    const unsigned short* arow = attTb + ((size_t)bt * N + itile * 16 + c16) * N;
    const short8 at0 = *(const short8*)(arow + 0 * 32 + q4 * 8);
    const short8 at1 = *(const short8*)(arow + 1 * 32 + q4 * 8);
    const short8 at2 = *(const short8*)(arow + 2 * 32 + q4 * 8);
    const short8 at3 = *(const short8*)(arow + 3 * 32 + q4 * 8);

    const int il0 = itile * 16 + q4 * 4;
    const f32x4 as4 = *(const f32x4*)(asum_g + (size_t)bt * N + il0);

    const unsigned short* whr = WfhT + cc * 64;
    const short8 wh0 = *(const short8*)(whr + q4 * 8);
    const short8 wh1 = *(const short8*)(whr + 32 + q4 * 8);
    const unsigned short* wvr = WfvT + cc * 64;
    const short8 wv0 = *(const short8*)(wvr + q4 * 8);
    const short8 wv1 = *(const short8*)(wvr + 32 + q4 * 8);
    const float bhc = bh[cc];
    const float bvc = bvb2[cc];

    const unsigned short* xpanel = xTb + (size_t)bt * N * CIN;

    // Phase 1: mh panel -> LDS ; mv tile for own itile -> accv.
    f32x4 accv = {0.f, 0.f, 0.f, 0.f};
#pragma unroll
    for (int nt8 = 0; nt8 < 8; ++nt8) {
        const unsigned short* xr = xpanel + (nt8 * 16 + c16) * CIN;
        const short8 a0 = *(const short8*)(xr + q4 * 8);
        const short8 a1 = *(const short8*)(xr + 32 + q4 * 8);
        f32x4 d = {0.f, 0.f, 0.f, 0.f};
        d = __builtin_amdgcn_mfma_f32_16x16x32_bf16(a0, wh0, d, 0, 0, 0);
        d = __builtin_amdgcn_mfma_f32_16x16x32_bf16(a1, wh1, d, 0, 0, 0);
        uint2 pk;
        pk.x = (unsigned)f2bf(d[0] + bhc) | ((unsigned)f2bf(d[1] + bhc) << 16);
        pk.y = (unsigned)f2bf(d[2] + bhc) | ((unsigned)f2bf(d[3] + bhc) << 16);
        *(uint2*)&mhT[cc][nt8 * 16 + q4 * 4] = pk;
        if (nt8 == itile) {
            accv = __builtin_amdgcn_mfma_f32_16x16x32_bf16(a0, wv0, accv, 0, 0, 0);
            accv = __builtin_amdgcn_mfma_f32_16x16x32_bf16(a1, wv1, accv, 0, 0, 0);
        }
    }
    __syncthreads();

    // Phase 2: einsum — A-frags already in registers.
    f32x4 acc = {0.f, 0.f, 0.f, 0.f};
    acc = __builtin_amdgcn_mfma_f32_16x16x32_bf16(at0, *(const short8*)(&mhT[cc][0 * 32 + q4 * 8]), acc, 0, 0, 0);
    acc = __builtin_amdgcn_mfma_f32_16x16x32_bf16(at1, *(const short8*)(&mhT[cc][1 * 32 + q4 * 8]), acc, 0, 0, 0);
    acc = __builtin_amdgcn_mfma_f32_16x16x32_bf16(at2, *(const short8*)(&mhT[cc][2 * 32 + q4 * 8]), acc, 0, 0, 0);
    acc = __builtin_amdgcn_mfma_f32_16x16x32_bf16(at3, *(const short8*)(&mhT[cc][3 * 32 + q4 * 8]), acc, 0, 0, 0);

    float* ob = out + (((size_t)b * COUT + cc) * N + il0) * T + t;
#pragma unroll
    for (int e = 0; e < 4; ++e) {
        ob[e * T] = acc[e] + as4[e] * (accv[e] + bvc);
    }
}

// ---------------------------------------------------------------------------
__global__ __launch_bounds__(256) void k_prep(
    const float* __restrict__ x,  const float* __restrict__ att,
    const float* __restrict__ W1, const float* __restrict__ b1,
    const float* __restrict__ W2, const float* __restrict__ b2,
    unsigned* __restrict__ xT32, unsigned* __restrict__ attT32,
    float* __restrict__ asum_g,
    unsigned short* __restrict__ WfvT, unsigned short* __restrict__ WfhT,
    float* __restrict__ bvb2, float* __restrict__ bh)
{
    __shared__ __align__(16) unsigned smem_u32[8320];
    prep_body(blockIdx.x, threadIdx.x, x, att, W1, b1, W2, b2,
              xT32, attT32, asum_g, WfvT, WfhT, bvb2, bh, smem_u32);
}

__global__ __launch_bounds__(256) void k_prep_amp(
    const float* __restrict__ x,  const float* __restrict__ att,
    const float* __restrict__ W1, const float* __restrict__ b1,
    const float* __restrict__ W2, const float* __restrict__ b2,
    unsigned* __restrict__ xT32, unsigned* __restrict__ attT32,
    float* __restrict__ asum_g,
    unsigned short* __restrict__ WfvT, unsigned short* __restrict__ WfhT,
    float* __restrict__ bvb2, float* __restrict__ bh)
{
    __shared__ __align__(16) unsigned smem_u32[8320];
    prep_body(blockIdx.x % PREP_BLOCKS, threadIdx.x, x, att, W1, b1, W2, b2,
              xT32, attT32, asum_g, WfvT, WfhT, bvb2, bh, smem_u32);
}

__global__ __launch_bounds__(256) void k_all(
    const unsigned short* __restrict__ xTb,
    const unsigned short* __restrict__ attTb,
    const unsigned short* __restrict__ WfvT,
    const unsigned short* __restrict__ WfhT,
    const float* __restrict__ bvb2, const float* __restrict__ bh,
    const float* __restrict__ asum_g,
    float* __restrict__ out)
{
    __shared__ __align__(8) unsigned short mhT[64][140];
    all_body(blockIdx.x, threadIdx.x, xTb, attTb, WfvT, WfhT, bvb2, bh,
             asum_g, out, mhT);
}

__global__ __launch_bounds__(256) void k_all_amp(
    const unsigned short* __restrict__ xTb,
    const unsigned short* __restrict__ attTb,
    const unsigned short* __restrict__ WfvT,
    const unsigned short* __restrict__ WfhT,
    const float* __restrict__ bvb2, const float* __restrict__ bh,
    const float* __restrict__ asum_g,
    float* __restrict__ out)
{
    __shared__ __align__(8) unsigned short mhT[64][140];
    all_body(blockIdx.x % ALL_BLOCKS, threadIdx.x, xTb, attTb, WfvT, WfhT,
             bvb2, bh, asum_g, out, mhT);
}

// ---------------------------------------------------------------------------
extern "C" void kernel_launch(void* const* d_in, const int* in_sizes, int n_in,
                              void* d_out, int out_size, void* d_ws, size_t ws_size,
                              hipStream_t stream)
{
    const float* x   = (const float*)d_in[0];
    const float* att = (const float*)d_in[1];
    const float* W1  = (const float*)d_in[2];
    const float* b1  = (const float*)d_in[3];
    const float* W2  = (const float*)d_in[4];
    const float* b2  = (const float*)d_in[5];
    float* out = (float*)d_out;

    char* ws = (char*)d_ws;
    unsigned*       xT32   = (unsigned*)ws;                        //   786,432 B
    unsigned*       attT32 = (unsigned*)(ws + 786432);             // 1,572,864 B
    float*          asum_g = (float*)(ws + 2359296);               //    24,576 B
    unsigned short* WfvT   = (unsigned short*)(ws + 2383872);      //     8,192 B
    unsigned short* WfhT   = (unsigned short*)(ws + 2392064);      //     8,192 B
    float*          bvb2   = (float*)(ws + 2400256);               //       256 B
    float*          bh     = (float*)(ws + 2400512);               //       256 B

    // Dummy region for amplified writes:
    char* dmy = ws + 8388608;
    unsigned*       xT32_d   = (unsigned*)dmy;
    unsigned*       attT32_d = (unsigned*)(dmy + 786432);
    float*          asum_d   = (float*)(dmy + 2359296);
    unsigned short* WfvT_d   = (unsigned short*)(dmy + 2383872);
    unsigned short* WfhT_d   = (unsigned short*)(dmy + 2392064);
    float*          bvb2_d   = (float*)(dmy + 2400256);
    float*          bh_d     = (float*)(dmy + 2400512);
    float*          out_d    = (float*)(dmy + 2400768);            // 3,145,728 B

    // Real pipeline (R13 + hoisted loads in k_all).
    k_prep<<<PREP_BLOCKS, 256, 0, stream>>>(x, att, W1, b1, W2, b2,
                                            xT32, attT32, asum_g,
                                            WfvT, WfhT, bvb2, bh);
    k_all<<<ALL_BLOCKS, 256, 0, stream>>>((const unsigned short*)xT32,
                                          (const unsigned short*)attT32,
                                          WfvT, WfhT, bvb2, bh, asum_g, out);

    // Diagnostic amplified dispatches (dummy writes; each gets a rocprof row).
    k_prep_amp<<<PREP_BLOCKS * AMP, 256, 0, stream>>>(
        x, att, W1, b1, W2, b2, xT32_d, attT32_d, asum_d,
        WfvT_d, WfhT_d, bvb2_d, bh_d);
    k_all_amp<<<ALL_BLOCKS * AMP, 256, 0, stream>>>(
        (const unsigned short*)xT32, (const unsigned short*)attT32,
        WfvT, WfhT, bvb2, bh, asum_g, out_d);
}

// Round 15
// 19.440 us; speedup vs baseline: 9.9198x; 9.9198x over previous
//
#include <hip/hip_runtime.h>

// Problem constants
constexpr int B_   = 2;
constexpr int CIN  = 64;
constexpr int N    = 128;
constexpr int T    = 24;
constexpr int HID  = 64;
constexpr int COUT = 64;
constexpr int NT   = N * T;             // 3072
constexpr int BT   = B_ * T;            // 48
constexpr int ATT_BLOCKS = B_ * N;      // 256
constexpr int XT_BLOCKS  = 32;
constexpr int WF_BLOCKS  = 16;
constexpr int PREP_BLOCKS = ATT_BLOCKS + XT_BLOCKS + WF_BLOCKS;  // 304
constexpr int ALL_BLOCKS  = BT * 8 * 4; // 1536 single-wave blocks

typedef __attribute__((ext_vector_type(8))) short short8;
typedef __attribute__((ext_vector_type(4))) float f32x4;

__device__ inline unsigned short f2bf(float f) {   // RNE float->bf16
    unsigned u = __float_as_uint(f);
    return (unsigned short)((u + 0x7FFFu + ((u >> 16) & 1u)) >> 16);
}

// ---------------------------------------------------------------------------
// k_prep: R13-identical (E_prep < 5.5us by R14 amplification).
//  [0,256):   att -> attT bf16 [bt][i][j] + asum f32
//  [256,288): x -> xT bf16 [bt][n][c']
//  [288,304): fused linear weights WfvT/WfhT + biases
// ---------------------------------------------------------------------------
__global__ __launch_bounds__(256) void k_prep(
    const float* __restrict__ x,
    const float* __restrict__ att,
    const float* __restrict__ W1,
    const float* __restrict__ b1,
    const float* __restrict__ W2,
    const float* __restrict__ b2,
    unsigned* __restrict__ xT32,
    unsigned* __restrict__ attT32,
    float* __restrict__ asum_g,
    unsigned short* __restrict__ WfvT,
    unsigned short* __restrict__ WfhT,
    float* __restrict__ bvb2,
    float* __restrict__ bh)
{
    __shared__ __align__(16) unsigned smem_u32[8320];
    const int tid = threadIdx.x;
    const int blk = blockIdx.x;

    if (blk < ATT_BLOCKS) {
        float* ts   = (float*)smem_u32;          // [128][25]
        float* psum = ts + 3200;                 // [24][8]
        const int b = blk >> 7;
        const int i = blk & 127;

        const float* ab = att + ((size_t)b * N + i) * NT;
#pragma unroll
        for (int u = 0; u < 12; ++u) {
            const int idx = tid + 256 * u;
            const int j = idx / T, t = idx - j * T;
            ts[j * 25 + t] = ab[idx];
        }
        __syncthreads();
#pragma unroll
        for (int u = 0; u < 6; ++u) {
            const int e2 = tid + 256 * u;
            const int t = e2 >> 6, jp = e2 & 63, j = jp * 2;
            const unsigned pk = (unsigned)f2bf(ts[j * 25 + t])
                              | ((unsigned)f2bf(ts[(j + 1) * 25 + t]) << 16);
            attT32[((size_t)(b * T + t) * N + i) * 64 + jp] = pk;
        }
        if (tid < 192) {
            const int t = tid >> 3, p = tid & 7;
            float s = 0.f;
#pragma unroll
            for (int q = 0; q < 16; ++q) s += ts[(p * 16 + q) * 25 + t];
            psum[t * 8 + p] = s;
        }
        __syncthreads();
        if (tid < T) {
            float s = 0.f;
#pragma unroll
            for (int p = 0; p < 8; ++p) s += psum[tid * 8 + p];
            asum_g[(size_t)(b * T + tid) * N + i] = s;
        }
    } else if (blk < ATT_BLOCKS + XT_BLOCKS) {
        const int tb = blk - ATT_BLOCKS;
        const int b  = tb >> 4;
        const int n0 = (tb & 15) * 8;
#pragma unroll
        for (int u = 0; u < 12; ++u) {
            const int vidx = tid + 256 * u;
            const int cp = vidx / 48, w48 = vidx - cp * 48;
            const float4 v = *(const float4*)(x + (size_t)(b * CIN + cp) * NT
                                              + n0 * T + w48 * 4);
            smem_u32[cp * 97 + w48 * 2]     = (unsigned)f2bf(v.x) | ((unsigned)f2bf(v.y) << 16);
            smem_u32[cp * 97 + w48 * 2 + 1] = (unsigned)f2bf(v.z) | ((unsigned)f2bf(v.w) << 16);
        }
        __syncthreads();
#pragma unroll
        for (int v = 0; v < 24; ++v) {
            const int oidx = tid + 256 * v;
            const int t = oidx >> 8, rem = oidx & 255;
            const int n = rem >> 5, cp = rem & 31;
            const int r = n * T + t;
            const unsigned w0 = smem_u32[(2 * cp) * 97 + (r >> 1)];
            const unsigned w1 = smem_u32[(2 * cp + 1) * 97 + (r >> 1)];
            const unsigned v0 = (r & 1) ? (w0 >> 16) : (w0 & 0xFFFFu);
            const unsigned v1 = (r & 1) ? (w1 >> 16) : (w1 & 0xFFFFu);
            xT32[((size_t)(b * T + t) * N + n0 + n) * 32 + cp] = v0 | (v1 << 16);
        }
    } else {
        const int wf   = blk - (ATT_BLOCKS + XT_BLOCKS);
        const int half = wf >> 3;
        const int c0   = (wf & 7) * 8;
        float* sW1 = (float*)smem_u32;          // [64][65]
        float* sW2 = sW1 + 64 * 65;             // [64][65]
#pragma unroll
        for (int u = 0; u < 16; ++u) {
            const int i = tid + 256 * u;
            const int r = i >> 6, q = i & 63;
            sW1[r * 65 + q] = W1[i];
            sW2[r * 65 + q] = W2[half * 4096 + i];
        }
        __syncthreads();

        const int c = c0 + (tid & 7);
        const int r = tid >> 3;
        float a0 = 0.f, a1 = 0.f;
#pragma unroll
        for (int q = 0; q < 64; ++q) {
            const float w2 = sW2[q * 65 + c];
            a0 += sW1[r * 65 + q] * w2;
            a1 += sW1[(r + 32) * 65 + q] * w2;
        }
        unsigned short* dst = half ? WfhT : WfvT;
        dst[c * 64 + r]      = f2bf(a0);
        dst[c * 64 + r + 32] = f2bf(a1);

        if (tid < 8) {
            const int cb = c0 + tid;
            float s = 0.f;
#pragma unroll
            for (int q = 0; q < 64; ++q) s += b1[q] * sW2[q * 65 + cb];
            if (half) bh[cb] = s;
            else      bvb2[cb] = s + b2[cb];
        }
    }
}

// ---------------------------------------------------------------------------
// k_all: 1536 single-wave blocks = (bt, itile, ctile). Per-wave work identical
// to one R13 wave, but: (a) no __syncthreads (mhT dataflow is wave-local;
// lgkmcnt ordering suffices), (b) 4x block parallelism (6 waves/CU),
// (c) upd written COALESCED to ws [bt][i][c] — the R14-diagnosed 5.5us
// scattered-store drain is gone (final transpose moved to k_out).
// ---------------------------------------------------------------------------
__global__ __launch_bounds__(64) void k_all(
    const unsigned short* __restrict__ xTb,
    const unsigned short* __restrict__ attTb,
    const unsigned short* __restrict__ WfvT,
    const unsigned short* __restrict__ WfhT,
    const float* __restrict__ bvb2,
    const float* __restrict__ bh,
    const float* __restrict__ asum_g,
    float* __restrict__ upd)
{
    __shared__ __align__(8) unsigned short mhT[16][140];   // 4.4 KB, wave-local

    const int blk   = blockIdx.x;
    const int ct    = blk & 3;           // c-tile
    const int itile = (blk >> 2) & 7;
    const int bt    = blk >> 5;

    const int lane = threadIdx.x & 63;
    const int c16  = lane & 15;
    const int q4   = lane >> 4;
    const int cc   = ct * 16 + c16;

    // Hoisted global loads — one latency epoch for everything.
    const unsigned short* arow = attTb + ((size_t)bt * N + itile * 16 + c16) * N;
    const short8 at0 = *(const short8*)(arow + 0 * 32 + q4 * 8);
    const short8 at1 = *(const short8*)(arow + 1 * 32 + q4 * 8);
    const short8 at2 = *(const short8*)(arow + 2 * 32 + q4 * 8);
    const short8 at3 = *(const short8*)(arow + 3 * 32 + q4 * 8);

    const int il0 = itile * 16 + q4 * 4;
    const f32x4 as4 = *(const f32x4*)(asum_g + (size_t)bt * N + il0);

    const unsigned short* whr = WfhT + cc * 64;
    const short8 wh0 = *(const short8*)(whr + q4 * 8);
    const short8 wh1 = *(const short8*)(whr + 32 + q4 * 8);
    const unsigned short* wvr = WfvT + cc * 64;
    const short8 wv0 = *(const short8*)(wvr + q4 * 8);
    const short8 wv1 = *(const short8*)(wvr + 32 + q4 * 8);
    const float bhc = bh[cc];
    const float bvc = bvb2[cc];

    const unsigned short* xpanel = xTb + (size_t)bt * N * CIN;

    // Phase 1: mh column-block (all n, this wave's 16 c) -> LDS; mv tile -> accv.
    f32x4 accv = {0.f, 0.f, 0.f, 0.f};
#pragma unroll
    for (int nt8 = 0; nt8 < 8; ++nt8) {
        const unsigned short* xr = xpanel + (nt8 * 16 + c16) * CIN;
        const short8 a0 = *(const short8*)(xr + q4 * 8);
        const short8 a1 = *(const short8*)(xr + 32 + q4 * 8);
        f32x4 d = {0.f, 0.f, 0.f, 0.f};
        d = __builtin_amdgcn_mfma_f32_16x16x32_bf16(a0, wh0, d, 0, 0, 0);
        d = __builtin_amdgcn_mfma_f32_16x16x32_bf16(a1, wh1, d, 0, 0, 0);
        uint2 pk;
        pk.x = (unsigned)f2bf(d[0] + bhc) | ((unsigned)f2bf(d[1] + bhc) << 16);
        pk.y = (unsigned)f2bf(d[2] + bhc) | ((unsigned)f2bf(d[3] + bhc) << 16);
        *(uint2*)&mhT[c16][nt8 * 16 + q4 * 4] = pk;
        if (nt8 == itile) {   // block-uniform branch
            accv = __builtin_amdgcn_mfma_f32_16x16x32_bf16(a0, wv0, accv, 0, 0, 0);
            accv = __builtin_amdgcn_mfma_f32_16x16x32_bf16(a1, wv1, accv, 0, 0, 0);
        }
    }
    // No barrier: cross-lane exchange is within this wave via LDS; the
    // compiler's lgkmcnt wait before the dependent ds_reads orders it.

    // Phase 2: einsum tile.
    f32x4 acc = {0.f, 0.f, 0.f, 0.f};
    acc = __builtin_amdgcn_mfma_f32_16x16x32_bf16(at0, *(const short8*)(&mhT[c16][0 * 32 + q4 * 8]), acc, 0, 0, 0);
    acc = __builtin_amdgcn_mfma_f32_16x16x32_bf16(at1, *(const short8*)(&mhT[c16][1 * 32 + q4 * 8]), acc, 0, 0, 0);
    acc = __builtin_amdgcn_mfma_f32_16x16x32_bf16(at2, *(const short8*)(&mhT[c16][2 * 32 + q4 * 8]), acc, 0, 0, 0);
    acc = __builtin_amdgcn_mfma_f32_16x16x32_bf16(at3, *(const short8*)(&mhT[c16][3 * 32 + q4 * 8]), acc, 0, 0, 0);

    // Epilogue: upd[bt][i][c] — 16-lane-consecutive coalesced stores.
    float* ub = upd + ((size_t)bt * N + il0) * COUT + cc;
#pragma unroll
    for (int e = 0; e < 4; ++e) {
        ub[e * COUT] = acc[e] + as4[e] * (accv[e] + bvc);
    }
}

// ---------------------------------------------------------------------------
// k_out: transpose upd[bt][i][c] -> out[b][c][i][t].  Block = (b,i).
// Reads 24 runs of 256 B; writes 64 runs of 96 B (R4-proven ~1.5us pattern).
// ---------------------------------------------------------------------------
__global__ __launch_bounds__(256) void k_out(
    const float* __restrict__ upd,
    float* __restrict__ out)
{
    __shared__ float ts[T][COUT + 1];

    const int tid = threadIdx.x;
    const int b   = blockIdx.x >> 7;
    const int i   = blockIdx.x & 127;

#pragma unroll
    for (int u = 0; u < 6; ++u) {
        const int idx = tid + 256 * u;           // t*64 + c
        const int t   = idx >> 6;
        const int c   = idx & 63;
        ts[t][c] = upd[((size_t)(b * T + t) * N + i) * COUT + c];
    }
    __syncthreads();
#pragma unroll
    for (int u = 0; u < 6; ++u) {
        const int idx = tid + 256 * u;           // c*24 + t
        const int c   = idx / T;
        const int t   = idx - c * T;
        out[((size_t)(b * COUT + c) * N + i) * T + t] = ts[t][c];
    }
}

// ---------------------------------------------------------------------------
extern "C" void kernel_launch(void* const* d_in, const int* in_sizes, int n_in,
                              void* d_out, int out_size, void* d_ws, size_t ws_size,
                              hipStream_t stream)
{
    const float* x   = (const float*)d_in[0];
    const float* att = (const float*)d_in[1];
    const float* W1  = (const float*)d_in[2];
    const float* b1  = (const float*)d_in[3];
    const float* W2  = (const float*)d_in[4];
    const float* b2  = (const float*)d_in[5];
    float* out = (float*)d_out;

    char* ws = (char*)d_ws;
    unsigned*       xT32   = (unsigned*)ws;                        //   786,432 B
    unsigned*       attT32 = (unsigned*)(ws + 786432);             // 1,572,864 B
    float*          asum_g = (float*)(ws + 2359296);               //    24,576 B
    unsigned short* WfvT   = (unsigned short*)(ws + 2383872);      //     8,192 B
    unsigned short* WfhT   = (unsigned short*)(ws + 2392064);      //     8,192 B
    float*          bvb2   = (float*)(ws + 2400256);               //       256 B
    float*          bh     = (float*)(ws + 2400512);               //       256 B
    float*          upd    = (float*)(ws + 2400768);               // 1,572,864 B

    k_prep<<<PREP_BLOCKS, 256, 0, stream>>>(x, att, W1, b1, W2, b2,
                                            xT32, attT32, asum_g,
                                            WfvT, WfhT, bvb2, bh);
    k_all<<<ALL_BLOCKS, 64, 0, stream>>>((const unsigned short*)xT32,
                                         (const unsigned short*)attT32,
                                         WfvT, WfhT, bvb2, bh, asum_g, upd);
    k_out<<<B_ * N, 256, 0, stream>>>(upd, out);
}